// Round 1
// baseline (939.978 us; speedup 1.0000x reference)
//
#include <hip/hip_runtime.h>

// Problem constants (from reference setup_inputs)
constexpr int NB = 32;      // batch
constexpr int NN = 4096;    // nodes
constexpr int NE = 16384;   // edges
// feat = NN*256 = 1048576; head outputs: v1=64, adv=12 -> 76 accumulators/batch

__device__ __forceinline__ float relu_(float x) { return fmaxf(x, 0.0f); }

// ---------------------------------------------------------------- init
__global__ void k_init(float* deg, int* cnt, int* fill) {
  int i = blockIdx.x * 256 + threadIdx.x;
  if (i < NN) { deg[i] = 1.0f; cnt[i] = 0; fill[i] = 0; }  // deg starts at self-loop weight 1
}

// ---------------------------------------------------------------- edge pass 1: degree + counts
__global__ void k_edge1(const int* __restrict__ ei, const float* __restrict__ ew,
                        float* deg, int* cnt) {
  int e = blockIdx.x * 256 + threadIdx.x;
  if (e < NE) {
    int d = ei[NE + e];
    atomicAdd(&deg[d], ew[e]);
    atomicAdd(&cnt[d], 1);
  }
}

// ---------------------------------------------------------------- scan: csr offsets + dinv
__global__ void k_scan(const float* __restrict__ deg, float* __restrict__ dinv,
                       const int* __restrict__ cnt, int* __restrict__ csr_off) {
  __shared__ int sd[1024];
  int t = threadIdx.x;
  int base = t * 4;
  int c0 = cnt[base], c1 = cnt[base+1], c2 = cnt[base+2], c3 = cnt[base+3];
  int s = c0 + c1 + c2 + c3;
  sd[t] = s;
  __syncthreads();
  for (int off = 1; off < 1024; off <<= 1) {
    int v = (t >= off) ? sd[t - off] : 0;
    __syncthreads();
    sd[t] += v;
    __syncthreads();
  }
  int excl = sd[t] - s;
  csr_off[base]     = excl;
  csr_off[base + 1] = excl + c0;
  csr_off[base + 2] = excl + c0 + c1;
  csr_off[base + 3] = excl + c0 + c1 + c2;
  if (t == 1023) csr_off[4096] = sd[1023];
  for (int i = base; i < base + 4; ++i) dinv[i] = rsqrtf(deg[i]);
}

// ---------------------------------------------------------------- edge pass 2: fill CSR with normalized weights
__global__ void k_fill(const int* __restrict__ ei, const float* __restrict__ ew,
                       const float* __restrict__ dinv, const int* __restrict__ csr_off,
                       int* fill, int* __restrict__ csr_src, float* __restrict__ csr_w) {
  int e = blockIdx.x * 256 + threadIdx.x;
  if (e < NE) {
    int s = ei[e], d = ei[NE + e];
    float wn = ew[e] * dinv[s] * dinv[d];
    int p = csr_off[d] + atomicAdd(&fill[d], 1);
    csr_src[p] = s;
    csr_w[p] = wn;
  }
}

// ---------------------------------------------------------------- g0 = agg(x), 16 features
__global__ __launch_bounds__(256) void k_agg16(
    const float* __restrict__ x, const float* __restrict__ dinv,
    const int* __restrict__ csr_off, const int* __restrict__ csr_src,
    const float* __restrict__ csr_w, float* __restrict__ g0) {
  int b = blockIdx.y;
  int nn = threadIdx.x >> 4, f = threadIdx.x & 15;
  int n = blockIdx.x * 16 + nn;
  float di = dinv[n];
  size_t base = ((size_t)b * NN + n) * 16;
  float acc = x[base + f] * di * di;  // self term: h/deg
  int e0 = csr_off[n], e1 = csr_off[n + 1];
  for (int e = e0; e < e1; ++e)
    acc = fmaf(csr_w[e], x[((size_t)b * NN + csr_src[e]) * 16 + f], acc);
  g0[base + f] = acc;
}

// ---------------------------------------------------------------- h1 = relu(g0 @ W1 + b1)   [16 -> 128]
__global__ __launch_bounds__(256) void k_gemm1(
    const float* __restrict__ g0, const float* __restrict__ W1,
    const float* __restrict__ b1, float* __restrict__ h1) {
  __shared__ float W1s[16 * 128];
  __shared__ float g0s[256];
  int b = blockIdx.y, tile = blockIdx.x, t = threadIdx.x;
  for (int i = t; i < 2048; i += 256) W1s[i] = W1[i];
  g0s[t] = g0[((size_t)b * NN + tile * 16) * 16 + t];
  __syncthreads();
  int k = t & 127, ng = t >> 7;
  float wreg[16];
#pragma unroll
  for (int f = 0; f < 16; ++f) wreg[f] = W1s[f * 128 + k];
  float bias = b1[k];
#pragma unroll
  for (int nn = 0; nn < 8; ++nn) {
    int nl = ng * 8 + nn;
    float acc = bias;
#pragma unroll
    for (int f = 0; f < 16; ++f) acc = fmaf(g0s[nl * 16 + f], wreg[f], acc);
    h1[((size_t)b * NN + tile * 16 + nl) * 128 + k] = relu_(acc);
  }
}

// ---------------------------------------------------------------- g1 = agg(h1), 128 features
__global__ __launch_bounds__(256) void k_agg128(
    const float* __restrict__ h1, const float* __restrict__ dinv,
    const int* __restrict__ csr_off, const int* __restrict__ csr_src,
    const float* __restrict__ csr_w, float* __restrict__ g1) {
  int b = blockIdx.y;
  int nn = threadIdx.x >> 7, c = threadIdx.x & 127;
  int n = blockIdx.x * 2 + nn;
  float di = dinv[n];
  float acc = h1[((size_t)b * NN + n) * 128 + c] * di * di;
  int e0 = csr_off[n], e1 = csr_off[n + 1];
  for (int e = e0; e < e1; ++e)
    acc = fmaf(csr_w[e], h1[((size_t)b * NN + csr_src[e]) * 128 + c], acc);
  g1[((size_t)b * NN + n) * 128 + c] = acc;
}

// ---------------------------------------------------------------- h2T[f][b] = relu(g1 @ W2 + b2)  [128 -> 256], transposed store
// block: 2 nodes x all 32 batches; 256 thr = 4 waves; thread: jq=t&63 (4 j's), bg=t>>6 (8 b's)
__global__ __launch_bounds__(256) void k_gemm2(
    const float* __restrict__ g1, const float* __restrict__ W2,
    const float* __restrict__ b2, float* __restrict__ h2T) {
  __shared__ float g1s[32 * 256];
  int t = threadIdx.x;
  int n0 = blockIdx.x * 2;
  for (int i = t; i < 8192; i += 256) {
    int b = i >> 8, r = i & 255;
    g1s[i] = g1[((size_t)b * NN + n0) * 128 + r];
  }
  __syncthreads();
  int jq = t & 63, bg = t >> 6, b0 = bg * 8;
  const float4* W2v = (const float4*)W2;
  const float2* g1s2 = (const float2*)g1s;
  float4 bv = ((const float4*)b2)[jq];
  for (int nn = 0; nn < 2; ++nn) {
    float acc[8][4];
#pragma unroll
    for (int bb = 0; bb < 8; ++bb) {
      acc[bb][0] = bv.x; acc[bb][1] = bv.y; acc[bb][2] = bv.z; acc[bb][3] = bv.w;
    }
    for (int c = 0; c < 128; c += 2) {
      float4 wA = W2v[c * 64 + jq];
      float4 wB = W2v[(c + 1) * 64 + jq];
#pragma unroll
      for (int bb = 0; bb < 8; ++bb) {
        float2 f2 = g1s2[(b0 + bb) * 128 + nn * 64 + (c >> 1)];
        acc[bb][0] = fmaf(wA.x, f2.x, acc[bb][0]); acc[bb][0] = fmaf(wB.x, f2.y, acc[bb][0]);
        acc[bb][1] = fmaf(wA.y, f2.x, acc[bb][1]); acc[bb][1] = fmaf(wB.y, f2.y, acc[bb][1]);
        acc[bb][2] = fmaf(wA.z, f2.x, acc[bb][2]); acc[bb][2] = fmaf(wB.z, f2.y, acc[bb][2]);
        acc[bb][3] = fmaf(wA.w, f2.x, acc[bb][3]); acc[bb][3] = fmaf(wB.w, f2.y, acc[bb][3]);
      }
    }
#pragma unroll
    for (int jj = 0; jj < 4; ++jj) {
      float4 lo, hi;
      lo.x = relu_(acc[0][jj]); lo.y = relu_(acc[1][jj]); lo.z = relu_(acc[2][jj]); lo.w = relu_(acc[3][jj]);
      hi.x = relu_(acc[4][jj]); hi.y = relu_(acc[5][jj]); hi.z = relu_(acc[6][jj]); hi.w = relu_(acc[7][jj]);
      float* dst0 = h2T + ((size_t)(n0 + nn) * 256 + jq * 4 + jj) * 32 + b0;
      *(float4*)dst0 = lo;
      *(float4*)(dst0 + 4) = hi;
    }
  }
}

// ---------------------------------------------------------------- head split-K: partials of feat@v1W and feat@advW
// block: 4 nodes (1024 f); wave w handles f = fbase + 4*i + w; lane l = k for v1 (64), k=l for adv when l<12
__global__ __launch_bounds__(256) void k_head(
    const float* __restrict__ h2T, const float* __restrict__ v1W,
    const float* __restrict__ advW, float* __restrict__ P) {
  __shared__ float red[4 * 2432];
  int t = threadIdx.x;
  int l = t & 63;
  int w = __builtin_amdgcn_readfirstlane(t >> 6);
  int fbase = blockIdx.x * 1024;
  float accv[32], acca[32];
#pragma unroll
  for (int i = 0; i < 32; ++i) { accv[i] = 0.0f; acca[i] = 0.0f; }
  bool adv_act = (l < 12);
  for (int i = 0; i < 256; ++i) {
    int f = fbase + (i << 2) + w;
    float wv = v1W[(size_t)f * 64 + l];
    float wa = adv_act ? advW[(size_t)f * 12 + l] : 0.0f;
    const float4* fr = (const float4*)(h2T + (size_t)f * 32);
#pragma unroll
    for (int bb = 0; bb < 8; ++bb) {
      float4 s = fr[bb];
      accv[4 * bb + 0] = fmaf(s.x, wv, accv[4 * bb + 0]);
      accv[4 * bb + 1] = fmaf(s.y, wv, accv[4 * bb + 1]);
      accv[4 * bb + 2] = fmaf(s.z, wv, accv[4 * bb + 2]);
      accv[4 * bb + 3] = fmaf(s.w, wv, accv[4 * bb + 3]);
      acca[4 * bb + 0] = fmaf(s.x, wa, acca[4 * bb + 0]);
      acca[4 * bb + 1] = fmaf(s.y, wa, acca[4 * bb + 1]);
      acca[4 * bb + 2] = fmaf(s.z, wa, acca[4 * bb + 2]);
      acca[4 * bb + 3] = fmaf(s.w, wa, acca[4 * bb + 3]);
    }
  }
#pragma unroll
  for (int bb = 0; bb < 32; ++bb) red[w * 2432 + bb * 64 + l] = accv[bb];
  __syncthreads();  // ensure v-region written before adv-region (different lanes touch same LDS bank region safely anyway; this also orders with readers)
  if (adv_act) {
#pragma unroll
    for (int bb = 0; bb < 32; ++bb) red[w * 2432 + 2048 + bb * 12 + l] = acca[bb];
  }
  __syncthreads();
  for (int o = t; o < 2432; o += 256) {
    float s = red[o] + red[2432 + o] + red[2 * 2432 + o] + red[3 * 2432 + o];
    P[(size_t)blockIdx.x * 2432 + o] = s;
  }
}

// ---------------------------------------------------------------- reduce partials -> Sv[32*64], Sa[32*12]
__global__ __launch_bounds__(256) void k_reduce(const float* __restrict__ P,
                                                float* __restrict__ Sv, float* __restrict__ Sa) {
  int o = blockIdx.x * 256 + threadIdx.x;
  if (o >= 2432) return;
  float s = 0.0f;
  for (int p = 0; p < 1024; ++p) s += P[(size_t)p * 2432 + o];
  if (o < 2048) Sv[o] = s;
  else Sa[o - 2048] = s;
}

// ---------------------------------------------------------------- final MLP + dueling combine
__global__ void k_final(const float* __restrict__ Sv, const float* __restrict__ Sa,
                        const float* __restrict__ v1b, const float* __restrict__ v2W,
                        const float* __restrict__ v2b, const float* __restrict__ v3W,
                        const float* __restrict__ v3b, const float* __restrict__ advb,
                        float* __restrict__ out) {
  int b = blockIdx.x, t = threadIdx.x;
  __shared__ float v1s[64], v2s[64], as_[12];
  __shared__ float v3s;
  v1s[t] = relu_(Sv[b * 64 + t] + v1b[t]);
  if (t < 12) as_[t] = relu_(Sa[b * 12 + t] + advb[t]);
  __syncthreads();
  float acc = v2b[t];
  for (int k = 0; k < 64; ++k) acc = fmaf(v1s[k], v2W[k * 64 + t], acc);
  v2s[t] = relu_(acc);
  __syncthreads();
  if (t == 0) {
    float v3 = v3b[0];
    for (int j = 0; j < 64; ++j) v3 = fmaf(v2s[j], v3W[j], v3);
    v3s = v3;
  }
  __syncthreads();
  if (t < 12) {
    int h = t >> 2;
    float m = 0.25f * (as_[h * 4] + as_[h * 4 + 1] + as_[h * 4 + 2] + as_[h * 4 + 3]);
    out[b * 12 + t] = v3s + as_[t] - m;
  }
}

// ================================================================ launcher
extern "C" void kernel_launch(void* const* d_in, const int* in_sizes, int n_in,
                              void* d_out, int out_size, void* d_ws, size_t ws_size,
                              hipStream_t stream) {
  (void)in_sizes; (void)n_in; (void)out_size; (void)ws_size;
  const float* x    = (const float*)d_in[0];
  const int*   ei   = (const int*)d_in[1];
  const float* ew   = (const float*)d_in[2];
  const float* W1   = (const float*)d_in[3];
  const float* b1   = (const float*)d_in[4];
  const float* W2   = (const float*)d_in[5];
  const float* b2   = (const float*)d_in[6];
  const float* advW = (const float*)d_in[7];
  const float* advb = (const float*)d_in[8];
  const float* v1W  = (const float*)d_in[9];
  const float* v1b  = (const float*)d_in[10];
  const float* v2W  = (const float*)d_in[11];
  const float* v2b  = (const float*)d_in[12];
  const float* v3W  = (const float*)d_in[13];
  const float* v3b  = (const float*)d_in[14];
  float* out = (float*)d_out;

  char* w8 = (char*)d_ws;
  // small region (< 16 MB)
  float* deg     = (float*)w8;                 // 4096
  float* dinv    = deg + 4096;                 // 4096
  int*   csr_off = (int*)(dinv + 4096);        // 4097 (padded to 4352)
  int*   cnt     = csr_off + 4352;             // 4096
  int*   fill    = cnt + 4096;                 // 4096
  int*   csr_src = fill + 4096;                // 16384
  float* csr_w   = (float*)(csr_src + NE);     // 16384
  float* P       = csr_w + NE;                 // 1024 * 2432 (~10 MB)
  float* Sv      = P + 1024 * 2432;            // 2048
  float* Sa      = Sv + 2048;                  // 384
  // big buffers
  float* g1  = (float*)(w8 + (size_t)16 * 1024 * 1024);  // 64 MB  [16..80 MB)
  float* g0  = (float*)(w8 + (size_t)80 * 1024 * 1024);  // 8 MB   [80..88 MB)
  float* h1  = g0 + 2097152;                             // 64 MB  [88..152 MB)
  float* h2T = g0;                                       // 128 MB [80..208 MB), reuses dead g0+h1

  k_init  <<<16, 256, 0, stream>>>(deg, cnt, fill);
  k_edge1 <<<64, 256, 0, stream>>>(ei, ew, deg, cnt);
  k_scan  <<<1, 1024, 0, stream>>>(deg, dinv, cnt, csr_off);
  k_fill  <<<64, 256, 0, stream>>>(ei, ew, dinv, csr_off, fill, csr_src, csr_w);
  k_agg16 <<<dim3(NN / 16, NB), 256, 0, stream>>>(x, dinv, csr_off, csr_src, csr_w, g0);
  k_gemm1 <<<dim3(NN / 16, NB), 256, 0, stream>>>(g0, W1, b1, h1);
  k_agg128<<<dim3(NN / 2, NB), 256, 0, stream>>>(h1, dinv, csr_off, csr_src, csr_w, g1);
  k_gemm2 <<<NN / 2, 256, 0, stream>>>(g1, W2, b2, h2T);
  k_head  <<<1024, 256, 0, stream>>>(h2T, v1W, advW, P);
  k_reduce<<<10, 256, 0, stream>>>(P, Sv, Sa);
  k_final <<<NB, 64, 0, stream>>>(Sv, Sa, v1b, v2W, v2b, v3W, v3b, advb, out);
}